// Round 9
// baseline (227.432 us; speedup 1.0000x reference)
//
#include <hip/hip_runtime.h>
#include <cstdint>

// Problem constants
#define LN_EPS 1e-5f

typedef _Float16 f16;
typedef _Float16 half4_t __attribute__((ext_vector_type(4)));
typedef _Float16 half8_t __attribute__((ext_vector_type(8)));
typedef __fp16 fp16v2 __attribute__((ext_vector_type(2)));
typedef float f32x4 __attribute__((ext_vector_type(4)));

// async global->LDS, 16B per lane; LDS dest = wave-uniform base + lane*16
__device__ __forceinline__ void gl_lds16(const void* g, void* l) {
    __builtin_amdgcn_global_load_lds(
        (__attribute__((address_space(1))) void*)(uintptr_t)g,
        (__attribute__((address_space(3))) void*)(uint32_t)(uintptr_t)l,
        16, 0, 0);
}

// pack 4 floats -> 4 f16 via v_cvt_pkrtz
__device__ __forceinline__ half4_t pack4(float a, float b, float c, float d) {
    fp16v2 lo = __builtin_amdgcn_cvt_pkrtz(a, b);
    fp16v2 hi = __builtin_amdgcn_cvt_pkrtz(c, d);
    half4_t r;
    r[0] = (f16)lo[0]; r[1] = (f16)lo[1]; r[2] = (f16)hi[0]; r[3] = (f16)hi[1];
    return r;
}

// ---------------------------------------------------------------- cast to f16, CHUNK-MAJOR planes
// Layout: M[p][row][8] with p = k>>3 (64 planes), so GEMM LDS tiles inherit 16B
// row stride -> 2-way (free) bank access on frag reads.
// W1h: p-stride 12288 (1536 rows); W2h: 4096 (512 rows); Xh: 65536 (8192 rows) x3 sections.
__global__ void k_cast(const float* __restrict__ W1f, const float* __restrict__ W2f,
                       const float* __restrict__ Xq, const float* __restrict__ Xk,
                       const float* __restrict__ Xv,
                       f16* __restrict__ W1h, f16* __restrict__ W2h, f16* __restrict__ Xh) {
    int t = blockIdx.x * 256 + threadIdx.x;   // 6656*256 = 1,703,936 threads, 8 f32 each
    const float* src;
    f16* dst;
    if (t < 98304) {                          // W1: 1536 rows x 64 planes
        int p = t & 63, r = t >> 6;
        src = W1f + (size_t)r * 512 + p * 8;
        dst = W1h + (size_t)p * 12288 + r * 8;
    } else if (t < 131072) {                  // W2: 512 rows x 64 planes
        int u = t - 98304;
        int p = u & 63, r = u >> 6;
        src = W2f + (size_t)r * 512 + p * 8;
        dst = W2h + (size_t)p * 4096 + r * 8;
    } else {                                  // X: 3 sections x 8192 rows x 64 planes
        int u2 = t - 131072;
        int s = u2 >> 19;
        int u = u2 & 524287;
        int r = u & 8191, p = u >> 13;
        const float* X = (s == 0) ? Xq : ((s == 1) ? Xk : Xv);
        src = X + (size_t)r * 512 + p * 8;
        dst = Xh + (size_t)s * 4194304 + (size_t)p * 65536 + r * 8;
    }
    float4 v0 = *(const float4*)src;
    float4 v1 = *(const float4*)(src + 4);
    half4_t h0 = pack4(v0.x, v0.y, v0.z, v0.w);
    half4_t h1 = pack4(v1.x, v1.y, v1.z, v1.w);
    half8_t h;
    #pragma unroll
    for (int j = 0; j < 4; ++j) { h[j] = h0[j]; h[j + 4] = h1[j]; }
    *(half8_t*)dst = h;
}

// ---------------------------------------------------------------- in-projection
// C = X @ W^T + b ; X,W chunk-major planes. LDS tiles [c4][128][8] (16B rows ->
// conflict-free frag reads). Outputs chunk-major per-(n,h): T[g][c][len][8].
// Q pre-scaled by beta*log2(e).
__global__ __launch_bounds__(256) void k_inproj(
    const f16* __restrict__ Xh, const f16* __restrict__ W1,
    const float* __restrict__ bias, const float* __restrict__ scaling,
    f16* __restrict__ Qg, f16* __restrict__ Kg, f16* __restrict__ Vg)
{
    __shared__ __align__(16) f16 Al[4096];   // [c4][128][8]
    __shared__ __align__(16) f16 Bl[4096];

    const int tid = threadIdx.x;
    const int m0 = blockIdx.x * 128;
    const int f0 = blockIdx.y * 128;          // global output-feature base [0,1536)
    const int sec = f0 >> 9;
    const f16* X = Xh + (size_t)sec * 4194304;
    f16* Ob = (sec == 0) ? Qg : ((sec == 1) ? Kg : Vg);

    const int wid = tid >> 6, ln = tid & 63, l15 = ln & 15, quad = ln >> 4;
    const int wm = wid >> 1, wn = wid & 1;

    f32x4 z4 = {0.f, 0.f, 0.f, 0.f};
    f32x4 acc[4][4];
    #pragma unroll
    for (int i = 0; i < 4; ++i)
        #pragma unroll
        for (int j = 0; j < 4; ++j) acc[i][j] = z4;

    for (int kt = 0; kt < 16; ++kt) {
        const int p = kt * 4 + wid;           // wave's plane
        gl_lds16(X + (size_t)p * 65536 + (size_t)(m0 + ln) * 8,       Al + wid * 1024);
        gl_lds16(X + (size_t)p * 65536 + (size_t)(m0 + 64 + ln) * 8,  Al + wid * 1024 + 512);
        gl_lds16(W1 + (size_t)p * 12288 + (size_t)(f0 + ln) * 8,      Bl + wid * 1024);
        gl_lds16(W1 + (size_t)p * 12288 + (size_t)(f0 + 64 + ln) * 8, Bl + wid * 1024 + 512);
        __syncthreads();

        half8_t a[4], b[4];
        #pragma unroll
        for (int i = 0; i < 4; ++i)
            a[i] = *(const half8_t*)(Al + quad * 1024 + (wm * 64 + i * 16 + l15) * 8);
        #pragma unroll
        for (int j = 0; j < 4; ++j)
            b[j] = *(const half8_t*)(Bl + quad * 1024 + (wn * 64 + j * 16 + l15) * 8);
        #pragma unroll
        for (int i = 0; i < 4; ++i)
            #pragma unroll
            for (int j = 0; j < 4; ++j)
                acc[i][j] = __builtin_amdgcn_mfma_f32_16x16x32_f16(b[j], a[i], acc[i][j], 0, 0, 0);
        __syncthreads();
    }

    // epilogue: C cols (l15) = X row, C rows (quad*4+r) = feature.
    #pragma unroll
    for (int j = 0; j < 4; ++j) {
        int fb = f0 + wn * 64 + j * 16;       // feature base of this 16-tile
        int floc = (fb & 511) + quad * 4;     // per-lane feature within section
        int hh = floc >> 5;
        int cc = (floc >> 3) & 3, e0 = floc & 7;
        float sc2 = (sec == 0) ? scaling[hh] * 1.44269504f : 1.0f;
        float4 bs4 = *(const float4*)(bias + fb + quad * 4);
        #pragma unroll
        for (int i = 0; i < 4; ++i) {
            int rm = m0 + wm * 64 + i * 16 + l15;
            int l = rm >> 2, nb = rm & 3;
            int gg = nb * 16 + hh;
            *(half4_t*)(Ob + (size_t)gg * 65536 + (size_t)cc * 16384 + (size_t)l * 8 + e0) =
                pack4((acc[i][j][0] + bs4.x) * sc2, (acc[i][j][1] + bs4.y) * sc2,
                      (acc[i][j][2] + bs4.z) * sc2, (acc[i][j][3] + bs4.w) * sc2);
        }
    }
}

// ---------------------------------------------------------------- LayerNorm K (in place) + V (normed, transposed)
// grid (32, 64): seg=64 s-rows, g. thread (s_l = t>>2, c = t&3) per matrix.
// Vg [g][c][2048][8] -> Vtg [g][seg][d=32][c'=8][8], c' = c_s XOR (d&7)
__global__ void k_norm_kv(f16* __restrict__ Kg, const f16* __restrict__ Vg,
                          const float* __restrict__ w, const float* __restrict__ b,
                          f16* __restrict__ Vtg) {
    __shared__ __align__(16) f16 T[32 * 64];   // [d][c'][8]
    const int t = threadIdx.x;
    const int seg = blockIdx.x, g = blockIdx.y;
    const int s_l = t >> 2, c = t & 3;
    const size_t base = (size_t)g * 65536 + (size_t)c * 16384 + (size_t)(seg * 64 + s_l) * 8;

    half8_t kv = *(const half8_t*)(Kg + base);
    half8_t vv = *(const half8_t*)(Vg + base);
    float kf[8], vf[8];
    float ks1 = 0.f, ks2 = 0.f, vs1 = 0.f, vs2 = 0.f;
    #pragma unroll
    for (int j = 0; j < 8; ++j) {
        kf[j] = (float)kv[j]; ks1 += kf[j]; ks2 += kf[j] * kf[j];
        vf[j] = (float)vv[j]; vs1 += vf[j]; vs2 += vf[j] * vf[j];
    }
    ks1 += __shfl_xor(ks1, 1); ks1 += __shfl_xor(ks1, 2);
    ks2 += __shfl_xor(ks2, 1); ks2 += __shfl_xor(ks2, 2);
    vs1 += __shfl_xor(vs1, 1); vs1 += __shfl_xor(vs1, 2);
    vs2 += __shfl_xor(vs2, 1); vs2 += __shfl_xor(vs2, 2);
    float kmu = ks1 * (1.f / 32.f), kvar = ks2 * (1.f / 32.f) - kmu * kmu;
    float vmu = vs1 * (1.f / 32.f), vvar = vs2 * (1.f / 32.f) - vmu * vmu;
    float krs = rsqrtf(kvar + LN_EPS), vrs = rsqrtf(vvar + LN_EPS);

    half8_t ky;
    int cs = s_l >> 3, es = s_l & 7;
    #pragma unroll
    for (int j = 0; j < 8; ++j) {
        int d = c * 8 + j;
        float wd = w[d], bd = b[d];
        ky[j] = (f16)((kf[j] - kmu) * krs * wd + bd);
        T[d * 64 + (cs ^ j) * 8 + es] = (f16)((vf[j] - vmu) * vrs * wd + bd);
    }
    *(half8_t*)(Kg + base) = ky;
    __syncthreads();
    int d_o = t >> 3, c_o = t & 7;
    half8_t out = *(const half8_t*)(T + d_o * 64 + c_o * 8);
    *(half8_t*)(Vtg + (size_t)(g * 32 + seg) * 2048 + d_o * 64 + c_o * 8) = out;
}

// ---------------------------------------------------------------- flash attention
// R6/R8-proven online-softmax kernel; grid (g, q-block) for XCD L2 locality.
// ONLY change vs R8: epilogue writes Og in chunk-major planes [p][8192 rows][8]
// (p = feature>>3) so k_outproj gets conflict-free staging.
__global__ __launch_bounds__(256, 4) void k_flash(
    const f16* __restrict__ Qg, const f16* __restrict__ Kg,
    const f16* __restrict__ Vtg, f16* __restrict__ Og)
{
    __shared__ __align__(16) char smem[32768];
    // Kb[2]: 0/4096 ; Vb[2]: 8192/12288 ; P: 16384 + wid*4096 (Q staged there)

    const int tid = threadIdx.x, wid = tid >> 6, ln = tid & 63;
    const int l15 = ln & 15, quad = ln >> 4, l8 = ln & 7;
    char* Pw = smem + 16384 + wid * 4096;
    const int g = blockIdx.x, h = g & 15, n = g >> 4;
    const int q0 = blockIdx.y * 128;

    // prologue: wave wid stages its chunk c=wid of Q (128 q), K0, V0
    const f16* Qb = Qg + (size_t)g * 65536 + (size_t)wid * 16384 + (size_t)q0 * 8;
    gl_lds16(Qb + (size_t)ln * 8,        smem + 16384 + wid * 2048);
    gl_lds16(Qb + (size_t)(64 + ln) * 8, smem + 16384 + wid * 2048 + 1024);
    const f16* kp = Kg + (size_t)g * 65536 + (size_t)wid * 16384;
    const f16* vp = Vtg + (size_t)(g * 32) * 2048 + wid * 512;
    gl_lds16(kp + (size_t)ln * 8, smem + wid * 1024);
    gl_lds16(vp + (size_t)ln * 8, smem + 8192 + wid * 1024);
    kp += 512;   // next tile
    vp += 2048;
    __builtin_amdgcn_s_waitcnt(0x0F70);   // vmcnt(0)
    __syncthreads();
    half8_t aq[2];
    #pragma unroll
    for (int i = 0; i < 2; ++i)
        aq[i] = *(const half8_t*)(smem + 16384 + quad * 2048 + (wid * 32 + i * 16 + l15) * 16);
    __syncthreads();   // all aq reads done before any P write (race fix)

    // ones A-fragment: row m=0 is all 1 -> MFMA accumulates column sums of B
    half8_t onesf;
    {
        f16 o = (l15 == 0) ? (f16)1.0f : (f16)0.0f;
        #pragma unroll
        for (int j = 0; j < 8; ++j) onesf[j] = o;
    }

    f32x4 z4 = {0.f, 0.f, 0.f, 0.f};
    f32x4 accO[2][2], accSum[2];
    accO[0][0] = z4; accO[0][1] = z4; accO[1][0] = z4; accO[1][1] = z4;
    accSum[0] = z4; accSum[1] = z4;
    float m_i[2] = {-1e30f, -1e30f};

    for (int st = 0; st < 32; ++st) {
        const int cur = st & 1;
        if (st < 31) {
            gl_lds16(kp + (size_t)ln * 8, smem + (cur ^ 1) * 4096 + wid * 1024);
            gl_lds16(vp + (size_t)ln * 8, smem + 8192 + (cur ^ 1) * 4096 + wid * 1024);
            kp += 512;
            vp += 2048;
        }
        const char* Kl = smem + cur * 4096;
        const char* Vt = smem + 8192 + cur * 4096;

        // S^T: A = K (m=s), B = Qscaled (n=q); already in exp2 units
        half8_t ak[4];
        #pragma unroll
        for (int mt = 0; mt < 4; ++mt)
            ak[mt] = *(const half8_t*)(Kl + quad * 1024 + (mt * 16 + l15) * 16);
        f32x4 accS[2][4];
        #pragma unroll
        for (int i = 0; i < 2; ++i)
            #pragma unroll
            for (int mt = 0; mt < 4; ++mt)
                accS[i][mt] = __builtin_amdgcn_mfma_f32_16x16x32_f16(ak[mt], aq[i], z4, 0, 0, 0);

        // per-q max (lane col l15); quad-reduce via shfl
        float mn[2];
        bool up = false;
        #pragma unroll
        for (int i = 0; i < 2; ++i) {
            float xm = fmaxf(fmaxf(accS[i][0][0], accS[i][0][1]),
                             fmaxf(accS[i][0][2], accS[i][0][3]));
            #pragma unroll
            for (int mt = 1; mt < 4; ++mt)
                xm = fmaxf(xm, fmaxf(fmaxf(accS[i][mt][0], accS[i][mt][1]),
                                     fmaxf(accS[i][mt][2], accS[i][mt][3])));
            xm = fmaxf(xm, __shfl_xor(xm, 16));
            xm = fmaxf(xm, __shfl_xor(xm, 32));
            up = up || (xm > m_i[i]);
            mn[i] = fmaxf(m_i[i], xm);
        }
        if (__ballot(up)) {   // wave-uniform: rescale only when some max rose
            #pragma unroll
            for (int i = 0; i < 2; ++i) {
                float alpha = __builtin_amdgcn_exp2f(m_i[i] - mn[i]);
                #pragma unroll
                for (int dt = 0; dt < 2; ++dt)
                    #pragma unroll
                    for (int r = 0; r < 4; ++r) accO[i][dt][r] *= alpha;
                #pragma unroll
                for (int r = 0; r < 4; ++r) accSum[i][r] *= alpha;
            }
        }
        m_i[0] = mn[0]; m_i[1] = mn[1];

        // exp2 + packed P store (swizzled chunks: bank-uniform b64 writes)
        #pragma unroll
        for (int i = 0; i < 2; ++i) {
            #pragma unroll
            for (int mt = 0; mt < 4; ++mt) {
                float p0 = __builtin_amdgcn_exp2f(accS[i][mt][0] - mn[i]);
                float p1 = __builtin_amdgcn_exp2f(accS[i][mt][1] - mn[i]);
                float p2 = __builtin_amdgcn_exp2f(accS[i][mt][2] - mn[i]);
                float p3 = __builtin_amdgcn_exp2f(accS[i][mt][3] - mn[i]);
                int ch = (mt * 2 + (quad >> 1)) ^ l8;
                *(half4_t*)(Pw + (i * 16 + l15) * 128 + ch * 16 + (quad & 1) * 8) =
                    pack4(p0, p1, p2, p3);
            }
        }

        // O^T += V^T·P^T and rowsum += 1^T·P^T (ones-frag MFMA)
        #pragma unroll
        for (int kt = 0; kt < 2; ++kt) {
            half8_t av[2], bp[2];
            #pragma unroll
            for (int dt = 0; dt < 2; ++dt) {
                int d = dt * 16 + l15;
                int cp = (kt * 4 + quad) ^ (l15 & 7);
                av[dt] = *(const half8_t*)(Vt + d * 128 + cp * 16);
            }
            #pragma unroll
            for (int i = 0; i < 2; ++i)
                bp[i] = *(const half8_t*)(Pw + (i * 16 + l15) * 128 +
                                          (((kt * 4 + quad) ^ l8) * 16));
            #pragma unroll
            for (int i = 0; i < 2; ++i) {
                #pragma unroll
                for (int dt = 0; dt < 2; ++dt)
                    accO[i][dt] = __builtin_amdgcn_mfma_f32_16x16x32_f16(av[dt], bp[i], accO[i][dt], 0, 0, 0);
                accSum[i] = __builtin_amdgcn_mfma_f32_16x16x32_f16(onesf, bp[i], accSum[i], 0, 0, 0);
            }
        }

        __builtin_amdgcn_s_waitcnt(0x0F70);   // drain prefetch DMA (R4 race fix)
        __syncthreads();
    }

    // epilogue: l_i lives in accSum[i][0] on quad-0 lanes; broadcast. Normalize,
    // transpose via wave-private LDS (32 rows x 80 B), store Og chunk-major:
    // plane p = (h*32+d)>>3 = h*4 + d/8, row rm = n*2048+l.
    #pragma unroll
    for (int i = 0; i < 2; ++i) {
        float li = __shfl(accSum[i][0], l15);
        float inv = 1.f / li;
        #pragma unroll
        for (int dt = 0; dt < 2; ++dt)
            *(half4_t*)(Pw + (i * 16 + l15) * 80 + (dt * 16 + quad * 4) * 2) =
                pack4(accO[i][dt][0] * inv, accO[i][dt][1] * inv,
                      accO[i][dt][2] * inv, accO[i][dt][3] * inv);
    }
    int q2 = ln >> 1, hf = ln & 1;
    half8_t o0 = *(const half8_t*)(Pw + q2 * 80 + hf * 32);       // d = hf*16 .. +7
    half8_t o1 = *(const half8_t*)(Pw + q2 * 80 + hf * 32 + 16);  // d = hf*16+8 .. +15
    size_t rm = (size_t)(n * 2048 + q0 + wid * 32 + q2);
    size_t basee = (size_t)(h * 4 + hf * 2) * 65536 + rm * 8;
    *(half8_t*)(Og + basee) = o0;
    *(half8_t*)(Og + basee + 65536) = o1;
}

// ---------------------------------------------------------------- out-projection
// Out = O @ W2^T + b ; O chunk-major planes [p][8192][8], W2 planes [p][512][8].
// Conflict-free LDS tiles [c4][128][8]. Out f32 rows l*4+n.
__global__ __launch_bounds__(256) void k_outproj(
    const f16* __restrict__ A, const f16* __restrict__ W2,
    const float* __restrict__ bias, float* __restrict__ Out)
{
    __shared__ __align__(16) f16 Al[4096];
    __shared__ __align__(16) f16 Bl[4096];

    const int tid = threadIdx.x;
    const int m0 = blockIdx.x * 128;
    const int f0 = blockIdx.y * 128;
    const int wid = tid >> 6, ln = tid & 63, l15 = ln & 15, quad = ln >> 4;
    const int wm = wid >> 1, wn = wid & 1;

    f32x4 z4 = {0.f, 0.f, 0.f, 0.f};
    f32x4 acc[4][4];
    #pragma unroll
    for (int i = 0; i < 4; ++i)
        #pragma unroll
        for (int j = 0; j < 4; ++j) acc[i][j] = z4;

    for (int kt = 0; kt < 16; ++kt) {
        const int p = kt * 4 + wid;
        gl_lds16(A + (size_t)p * 65536 + (size_t)(m0 + ln) * 8,      Al + wid * 1024);
        gl_lds16(A + (size_t)p * 65536 + (size_t)(m0 + 64 + ln) * 8, Al + wid * 1024 + 512);
        gl_lds16(W2 + (size_t)p * 4096 + (size_t)(f0 + ln) * 8,      Bl + wid * 1024);
        gl_lds16(W2 + (size_t)p * 4096 + (size_t)(f0 + 64 + ln) * 8, Bl + wid * 1024 + 512);
        __syncthreads();

        half8_t a[4], b[4];
        #pragma unroll
        for (int i = 0; i < 4; ++i)
            a[i] = *(const half8_t*)(Al + quad * 1024 + (wm * 64 + i * 16 + l15) * 8);
        #pragma unroll
        for (int j = 0; j < 4; ++j)
            b[j] = *(const half8_t*)(Bl + quad * 1024 + (wn * 64 + j * 16 + l15) * 8);
        #pragma unroll
        for (int i = 0; i < 4; ++i)
            #pragma unroll
            for (int j = 0; j < 4; ++j)
                acc[i][j] = __builtin_amdgcn_mfma_f32_16x16x32_f16(b[j], a[i], acc[i][j], 0, 0, 0);
        __syncthreads();
    }

    #pragma unroll
    for (int j = 0; j < 4; ++j) {
        int fb = f0 + wn * 64 + j * 16;
        float4 bs4 = *(const float4*)(bias + fb + quad * 4);
        #pragma unroll
        for (int i = 0; i < 4; ++i) {
            int rm = m0 + wm * 64 + i * 16 + l15;
            int orow = (rm & 2047) * 4 + (rm >> 11);
            float4 o;
            o.x = acc[i][j][0] + bs4.x;
            o.y = acc[i][j][1] + bs4.y;
            o.z = acc[i][j][2] + bs4.z;
            o.w = acc[i][j][3] + bs4.w;
            *(float4*)(Out + (size_t)orow * 512 + fb + quad * 4) = o;
        }
    }
}

// ---------------------------------------------------------------- launch
extern "C" void kernel_launch(void* const* d_in, const int* in_sizes, int n_in,
                              void* d_out, int out_size, void* d_ws, size_t ws_size,
                              hipStream_t stream) {
    const float* query   = (const float*)d_in[0];
    const float* key_in  = (const float*)d_in[1];
    const float* value   = (const float*)d_in[2];
    const float* scaling = (const float*)d_in[3];
    const float* ipw     = (const float*)d_in[4];
    const float* ipb     = (const float*)d_in[5];
    const float* pnw     = (const float*)d_in[6];
    const float* pnb     = (const float*)d_in[7];
    const float* opw     = (const float*)d_in[8];
    const float* opb     = (const float*)d_in[9];
    float* out = (float*)d_out;

    // workspace (f16 element offsets), same 52,428,800 B footprint as R8:
    //   Qg 0 / Kg 4,194,304 / Vg 8,388,608 (each 4,194,304)
    //   W1 12,582,912 (786,432) / W2 13,369,344 (262,144)
    //   Xh 13,631,488 (12,582,912; dead after k_inproj)
    //   Vtg aliases Xh head; Og aliases Vg (dead after k_norm_kv)
    f16* Qg  = (f16*)d_ws;
    f16* Kg  = Qg + (size_t)4194304;
    f16* Vg  = Qg + (size_t)8388608;
    f16* W1  = Qg + (size_t)12582912;
    f16* W2  = Qg + (size_t)13369344;
    f16* Xh  = Qg + (size_t)13631488;
    f16* Vtg = Xh;   // alias (Xh consumed before k_norm_kv writes Vtg)
    f16* Og  = Vg;   // alias

    k_cast<<<6656, 256, 0, stream>>>(ipw, opw, query, key_in, value, W1, W2, Xh);
    k_inproj<<<dim3(64, 12), 256, 0, stream>>>(Xh, W1, ipb, scaling, Qg, Kg, Vg);
    k_norm_kv<<<dim3(32, 64), 256, 0, stream>>>(Kg, Vg, pnw, pnb, Vtg);
    k_flash<<<dim3(64, 16), 256, 0, stream>>>(Qg, Kg, Vtg, Og);
    k_outproj<<<dim3(64, 4), 256, 0, stream>>>(Og, W2, opb, out);
}